// Round 14
// baseline (448.132 us; speedup 1.0000x reference)
//
#include <hip/hip_runtime.h>

// LIF layer: B=64, T=256, P=1024, D=1024. reference ignores prv_voltage.
// d_out = [voltage (B*T*D fp32) | spikes (B*T*D fp32)].
//
// NUMERICS LOCKED (R10): currents[row,d] =
//   (asc-p f32 single-acc sum over active p in [0,512))
// + (asc-p f32 single-acc sum over active p in [512,1024)), f32;
// scan = f32 separate mul-then-add, >=1.0, reset-to-zero.
//
// R14: R13's LDS design was right (LDS pipe floor ~130us < R12's 279us L2
// floor) but the schedule was serial (stage -> drain -> compute, x16, no
// overlap, 2 blocks/CU) -> 433us. Fix = double-buffer (T3 2-phase recipe):
// 32 chunks of 32 p-rows (32KB each), STAGE(next) issued BEFORE COMPUTE(cur),
// one vmcnt(0)+barrier per chunk. Chunks 0-15 fold ascending into accA
// (panel0), 16-31 into accB (panel1); accA+accB at the end — bitwise == R10.

#define LIF_B 64
#define LIF_T 256
#define LIF_P 1024
#define LIF_D 1024
#define LIF_N ((size_t)LIF_B * LIF_T * LIF_D)

__global__ __launch_bounds__(256) void lif_currents_kernel(
    const float* __restrict__ spikes,   // (B*T, P)
    const float* __restrict__ W,        // (P, D)
    float* __restrict__ cur_out)        // (B*T, D) — voltage region of d_out
{
    __shared__ float4 wbuf[2][32][64];               // 2 x 32 KB double buffer
    __shared__ unsigned long long masks[32][16];     // 4 KB

    const int tid  = threadIdx.x;
    const int lane = tid & 63;
    const int wave = tid >> 6;
    const int bid  = blockIdx.x;        // ds-major: bid = ds*512 + rg
    const int ds   = bid >> 9;          // 0..3
    const int rg   = bid & 511;         // 0..511
    const int row0 = rg << 5;           // 32 rows per block
    const int dbase = ds << 8;          // 256-col slice

    // ---- Phase A: per-row activity masks (wave handles its 8 rows)
    for (int i = 0; i < 8; ++i) {
        const int rl = (wave << 3) + i;
        const float* srow = spikes + (size_t)(row0 + rl) * LIF_P;
        #pragma unroll 4
        for (int c = 0; c < 16; ++c) {
            const float sv = srow[(c << 6) + lane];
            const unsigned long long m = __ballot(sv != 0.0f);
            if (lane == 0) masks[rl][c] = m;
        }
    }

    float4 accA[8], accB[8];
    #pragma unroll
    for (int i = 0; i < 8; ++i) {
        accA[i] = make_float4(0.f, 0.f, 0.f, 0.f);
        accB[i] = make_float4(0.f, 0.f, 0.f, 0.f);
    }

    #define LIF_ACC4(A, WV)                                                   \
        (A).x = __fadd_rn((A).x, (WV).x); (A).y = __fadd_rn((A).y, (WV).y);   \
        (A).z = __fadd_rn((A).z, (WV).z); (A).w = __fadd_rn((A).w, (WV).w);

    // stage chunk C (32 p-rows x 256 cols = 32 KB) into wbuf[BUF];
    // wave stages its 8 p-rows, 1 KB each (wave-uniform LDS base + lane*16).
    #define LIF_STAGE(BUF, C)                                                 \
    {                                                                         \
        const int pl0 = (wave << 3);                                          \
        const float* gsrc = W + ((size_t)((((C) << 5) + pl0)) << 10)          \
                              + dbase + (lane << 2);                          \
        _Pragma("unroll")                                                     \
        for (int i = 0; i < 8; ++i) {                                         \
            __builtin_amdgcn_global_load_lds(                                 \
                (const __attribute__((address_space(1))) void*)(gsrc + ((size_t)i << 10)), \
                (__attribute__((address_space(3))) void*)(&wbuf[(BUF)][pl0 + i][0]), \
                16, 0, 0);                                                    \
        }                                                                     \
    }

    // walk this wave's 8 rows for 32-p chunk C, folding into ACC (ascending)
    #define LIF_COMPUTE(BUF, C, ACC)                                         \
    {                                                                         \
        const int half = (C) & 1;                                             \
        _Pragma("unroll")                                                     \
        for (int i = 0; i < 8; ++i) {                                         \
            const unsigned long long m64 = masks[(wave << 3) + i][(C) >> 1];  \
            unsigned mm = half ? (unsigned)(m64 >> 32) : (unsigned)m64;       \
            mm = __builtin_amdgcn_readfirstlane(mm);                          \
            while (mm) {                                                      \
                const int p0 = __builtin_ctz(mm); mm &= (mm - 1);             \
                const float4 w0 = wbuf[(BUF)][p0][lane];                      \
                if (mm) {                                                     \
                    const int p1 = __builtin_ctz(mm); mm &= (mm - 1);         \
                    const float4 w1 = wbuf[(BUF)][p1][lane];                  \
                    if (mm) {                                                 \
                        const int p2 = __builtin_ctz(mm); mm &= (mm - 1);     \
                        const float4 w2 = wbuf[(BUF)][p2][lane];              \
                        if (mm) {                                             \
                            const int p3 = __builtin_ctz(mm); mm &= (mm - 1); \
                            const float4 w3 = wbuf[(BUF)][p3][lane];          \
                            LIF_ACC4(ACC[i], w0) LIF_ACC4(ACC[i], w1)         \
                            LIF_ACC4(ACC[i], w2) LIF_ACC4(ACC[i], w3)         \
                        } else {                                              \
                            LIF_ACC4(ACC[i], w0) LIF_ACC4(ACC[i], w1)         \
                            LIF_ACC4(ACC[i], w2)                              \
                        }                                                     \
                    } else { LIF_ACC4(ACC[i], w0) LIF_ACC4(ACC[i], w1) }      \
                } else { LIF_ACC4(ACC[i], w0) }                               \
            }                                                                 \
        }                                                                     \
    }

    // ---- pipelined main loop: stage(c+1) issued before compute(c)
    __syncthreads();                     // masks visible
    LIF_STAGE(0, 0)
    asm volatile("s_waitcnt vmcnt(0)" ::: "memory");
    __syncthreads();

    #pragma unroll 1
    for (int c = 0; c < 32; ++c) {
        const int cur = c & 1;
        if (c + 1 < 32) LIF_STAGE(cur ^ 1, c + 1)
        if (c < 16) { LIF_COMPUTE(cur, c, accA) }
        else        { LIF_COMPUTE(cur, c, accB) }
        asm volatile("s_waitcnt vmcnt(0)" ::: "memory");
        __syncthreads();
    }

    #undef LIF_COMPUTE
    #undef LIF_STAGE
    #undef LIF_ACC4

    // epilogue: locked panel association P0 + P1, then store
    #pragma unroll
    for (int i = 0; i < 8; ++i) {
        float4 c4;
        c4.x = __fadd_rn(accA[i].x, accB[i].x);
        c4.y = __fadd_rn(accA[i].y, accB[i].y);
        c4.z = __fadd_rn(accA[i].z, accB[i].z);
        c4.w = __fadd_rn(accA[i].w, accB[i].w);
        const int row = row0 + (wave << 3) + i;
        *reinterpret_cast<float4*>(cur_out + (size_t)row * LIF_D + dbase + (lane << 2)) = c4;
    }
}

__global__ __launch_bounds__(256) void lif_scan_kernel(
    float* __restrict__ voltage,        // in: staged currents, out: v_new
    float* __restrict__ spikes_out)     // out: binary spikes
{
    const int tid = blockIdx.x * 256 + threadIdx.x;   // 0 .. B*D-1
    const int b = tid >> 10;
    const int d = tid & (LIF_D - 1);

    float v = 0.0f;
    const size_t base = ((size_t)b * LIF_T) * LIF_D + d;

    float p0 = voltage[base + 0 * (size_t)LIF_D];
    float p1 = voltage[base + 1 * (size_t)LIF_D];
    float p2 = voltage[base + 2 * (size_t)LIF_D];
    float p3 = voltage[base + 3 * (size_t)LIF_D];

    for (int t = 0; t < LIF_T; t += 4) {
        const float c0 = p0, c1 = p1, c2 = p2, c3 = p3;
        if (t + 4 < LIF_T) {
            p0 = voltage[base + (size_t)(t + 4) * LIF_D];
            p1 = voltage[base + (size_t)(t + 5) * LIF_D];
            p2 = voltage[base + (size_t)(t + 6) * LIF_D];
            p3 = voltage[base + (size_t)(t + 7) * LIF_D];
        }
        const size_t i0 = base + (size_t)t * LIF_D;
        {
            const float vn = __fadd_rn(__fmul_rn(0.9f, v), c0);
            const bool f = (vn >= 1.0f);
            voltage[i0 + 0 * (size_t)LIF_D] = vn;
            spikes_out[i0 + 0 * (size_t)LIF_D] = f ? 1.0f : 0.0f;
            v = f ? 0.0f : vn;
        }
        {
            const float vn = __fadd_rn(__fmul_rn(0.9f, v), c1);
            const bool f = (vn >= 1.0f);
            voltage[i0 + 1 * (size_t)LIF_D] = vn;
            spikes_out[i0 + 1 * (size_t)LIF_D] = f ? 1.0f : 0.0f;
            v = f ? 0.0f : vn;
        }
        {
            const float vn = __fadd_rn(__fmul_rn(0.9f, v), c2);
            const bool f = (vn >= 1.0f);
            voltage[i0 + 2 * (size_t)LIF_D] = vn;
            spikes_out[i0 + 2 * (size_t)LIF_D] = f ? 1.0f : 0.0f;
            v = f ? 0.0f : vn;
        }
        {
            const float vn = __fadd_rn(__fmul_rn(0.9f, v), c3);
            const bool f = (vn >= 1.0f);
            voltage[i0 + 3 * (size_t)LIF_D] = vn;
            spikes_out[i0 + 3 * (size_t)LIF_D] = f ? 1.0f : 0.0f;
            v = f ? 0.0f : vn;
        }
    }
}

extern "C" void kernel_launch(void* const* d_in, const int* in_sizes, int n_in,
                              void* d_out, int out_size, void* d_ws, size_t ws_size,
                              hipStream_t stream) {
    (void)in_sizes; (void)n_in; (void)out_size; (void)d_ws; (void)ws_size;

    // d_in[0] = prv_voltage (UNUSED by reference)
    const float* spikes = (const float*)d_in[1];   // (B,T,P) binary fp32
    const float* W      = (const float*)d_in[2];   // (P,D) fp32

    float* out        = (float*)d_out;
    float* voltage    = out;                       // N floats (stages currents)
    float* spikes_out = out + LIF_N;               // N floats

    lif_currents_kernel<<<2048, 256, 0, stream>>>(spikes, W, voltage);
    lif_scan_kernel<<<(LIF_B * LIF_D) / 256, 256, 0, stream>>>(voltage, spikes_out);
}

// Round 16
// 302.198 us; speedup vs baseline: 1.4829x; 1.4829x over previous
//
#include <hip/hip_runtime.h>

// LIF layer: B=64, T=256, P=1024, D=1024. reference ignores prv_voltage.
// d_out = [voltage (B*T*D fp32) | spikes (B*T*D fp32)].
//
// NUMERICS LOCKED (R10): currents[row,d] =
//   (asc-p f32 single-acc sum over active p in [0,512))
// + (asc-p f32 single-acc sum over active p in [512,1024)), f32;
// scan = f32 separate mul-then-add, >=1.0, reset-to-zero.
//
// R16 = R15 with the compile fix: __builtin_nontemporal_store needs a NATIVE
// clang vector (ext_vector_type), not HIP_vector_type<float,4>. Theory
// unchanged: R12's gather is slowed by W (4MiB = one XCD L2) being evicted
// ~50x/dispatch by streaming spikes-reads + currents-writes (FETCH 213MB).
// nt hints on all streaming accesses keep W L2-resident.

#define LIF_B 64
#define LIF_T 256
#define LIF_P 1024
#define LIF_D 1024
#define LIF_N ((size_t)LIF_B * LIF_T * LIF_D)

typedef float f32x4 __attribute__((ext_vector_type(4)));

__global__ __launch_bounds__(256) void lif_currents_kernel(
    const float* __restrict__ spikes,   // (B*T, P)
    const float* __restrict__ W,        // (P, D)
    float* __restrict__ cur_out)        // (B*T, D) — voltage region of d_out
{
    __shared__ unsigned long long smask[16];
    __shared__ int plist[1024];          // panel0 at [0..c0), panel1 at [512..512+c1)
    __shared__ int scnt[2];

    const int row  = blockIdx.x;          // 0 .. B*T-1
    const int tid  = threadIdx.x;
    const int lane = tid & 63;
    const int wave = tid >> 6;            // 4 waves x 256 d-columns
    const int dbase = wave << 8;

    const float* srow = spikes + (size_t)row * LIF_P;
    const float* wcol = W + dbase + (lane << 2);   // this lane's 4 columns

    // Phase 1: cooperative mask build — wave w handles chunks 4w..4w+3.
    // spikes are streaming (read once): non-temporal, don't evict W from L2.
    for (int jj = 0; jj < 4; ++jj) {
        const int j = (wave << 2) + jj;
        const float sv = __builtin_nontemporal_load(&srow[(j << 6) + lane]);
        const unsigned long long m = __ballot(sv != 0.0f);
        if (lane == 0) smask[j] = m;
    }
    __syncthreads();

    // Phase 2: wave 0, lanes 0..15 build ascending p-lists (one chunk each).
    if (wave == 0) {
        unsigned long long m = (lane < 16) ? smask[lane] : 0ULL;
        const int pc = __popcll(m);
        int s = pc;                       // inclusive prefix within 8-lane group
        for (int d = 1; d < 8; d <<= 1) {
            const int vps = __shfl_up(s, d, 8);
            if ((lane & 7) >= d) s += vps;
        }
        if (lane == 7)  scnt[0] = s;
        if (lane == 15) scnt[1] = s;
        if (lane < 16) {
            int idx = ((lane < 8) ? 0 : 512) + (s - pc);
            const int pb = lane << 6;
            while (m) {
                plist[idx++] = pb + __builtin_ctzll(m);
                m &= (m - 1);
            }
        }
    }
    __syncthreads();

    const int c0 = scnt[0];
    const int c1 = scnt[1];

    float a0x=0.f,a0y=0.f,a0z=0.f,a0w=0.f;
    float a1x=0.f,a1y=0.f,a1z=0.f,a1w=0.f;

    #define LIF_ACC(AX,AY,AZ,AW,WV)                                             \
        AX = __fadd_rn(AX, (WV).x); AY = __fadd_rn(AY, (WV).y);                  \
        AZ = __fadd_rn(AZ, (WV).z); AW = __fadd_rn(AW, (WV).w);

    #define LIF_PANEL(BASE, CNT, AX,AY,AZ,AW)                                    \
    {                                                                            \
        int i = 0;                                                               \
        for (; i + 4 <= (CNT); i += 4) {                                         \
            const int4 ps = *reinterpret_cast<const int4*>(&plist[(BASE) + i]);  \
            const float4 w0 = *reinterpret_cast<const float4*>(wcol + ((size_t)ps.x << 10)); \
            const float4 w1 = *reinterpret_cast<const float4*>(wcol + ((size_t)ps.y << 10)); \
            const float4 w2 = *reinterpret_cast<const float4*>(wcol + ((size_t)ps.z << 10)); \
            const float4 w3 = *reinterpret_cast<const float4*>(wcol + ((size_t)ps.w << 10)); \
            LIF_ACC(AX,AY,AZ,AW, w0) LIF_ACC(AX,AY,AZ,AW, w1)                    \
            LIF_ACC(AX,AY,AZ,AW, w2) LIF_ACC(AX,AY,AZ,AW, w3)                    \
        }                                                                        \
        for (; i < (CNT); ++i) {                                                 \
            const int p = plist[(BASE) + i];                                     \
            const float4 wv = *reinterpret_cast<const float4*>(wcol + ((size_t)p << 10)); \
            LIF_ACC(AX,AY,AZ,AW, wv)                                             \
        }                                                                        \
    }

    LIF_PANEL(0,   c0, a0x,a0y,a0z,a0w)   // p in [0, 512), ascending
    LIF_PANEL(512, c1, a1x,a1y,a1z,a1w)   // p in [512, 1024), ascending
    #undef LIF_PANEL
    #undef LIF_ACC

    // Panel association: P0 + P1, plain f32 add (locked).
    f32x4 c;
    c.x = __fadd_rn(a0x, a1x);
    c.y = __fadd_rn(a0y, a1y);
    c.z = __fadd_rn(a0z, a1z);
    c.w = __fadd_rn(a0w, a1w);

    // currents store is streaming: non-temporal (keeps W resident in L2).
    __builtin_nontemporal_store(
        c, reinterpret_cast<f32x4*>(cur_out + (size_t)row * LIF_D + dbase + (lane << 2)));
}

__global__ __launch_bounds__(256) void lif_scan_kernel(
    float* __restrict__ voltage,        // in: staged currents, out: v_new
    float* __restrict__ spikes_out)     // out: binary spikes
{
    const int tid = blockIdx.x * 256 + threadIdx.x;   // 0 .. B*D-1
    const int b = tid >> 10;
    const int d = tid & (LIF_D - 1);

    float v = 0.0f;
    const size_t base = ((size_t)b * LIF_T) * LIF_D + d;

    // 4-deep prefetch; all accesses streaming -> non-temporal.
    float p0 = __builtin_nontemporal_load(&voltage[base + 0*(size_t)LIF_D]);
    float p1 = __builtin_nontemporal_load(&voltage[base + 1*(size_t)LIF_D]);
    float p2 = __builtin_nontemporal_load(&voltage[base + 2*(size_t)LIF_D]);
    float p3 = __builtin_nontemporal_load(&voltage[base + 3*(size_t)LIF_D]);

    for (int t = 0; t < LIF_T; t += 4) {
        const float c0 = p0, c1 = p1, c2 = p2, c3 = p3;
        if (t + 4 < LIF_T) {
            p0 = __builtin_nontemporal_load(&voltage[base + (size_t)(t + 4) * LIF_D]);
            p1 = __builtin_nontemporal_load(&voltage[base + (size_t)(t + 5) * LIF_D]);
            p2 = __builtin_nontemporal_load(&voltage[base + (size_t)(t + 6) * LIF_D]);
            p3 = __builtin_nontemporal_load(&voltage[base + (size_t)(t + 7) * LIF_D]);
        }
        const size_t i0 = base + (size_t)t * LIF_D;
        // numpy scan: separate f32 mul then add (no FMA contraction) — locked.
        {
            const float vn = __fadd_rn(__fmul_rn(0.9f, v), c0);
            const bool f = (vn >= 1.0f);
            __builtin_nontemporal_store(vn, &voltage[i0 + 0*(size_t)LIF_D]);
            __builtin_nontemporal_store(f ? 1.0f : 0.0f, &spikes_out[i0 + 0*(size_t)LIF_D]);
            v = f ? 0.0f : vn;
        }
        {
            const float vn = __fadd_rn(__fmul_rn(0.9f, v), c1);
            const bool f = (vn >= 1.0f);
            __builtin_nontemporal_store(vn, &voltage[i0 + 1*(size_t)LIF_D]);
            __builtin_nontemporal_store(f ? 1.0f : 0.0f, &spikes_out[i0 + 1*(size_t)LIF_D]);
            v = f ? 0.0f : vn;
        }
        {
            const float vn = __fadd_rn(__fmul_rn(0.9f, v), c2);
            const bool f = (vn >= 1.0f);
            __builtin_nontemporal_store(vn, &voltage[i0 + 2*(size_t)LIF_D]);
            __builtin_nontemporal_store(f ? 1.0f : 0.0f, &spikes_out[i0 + 2*(size_t)LIF_D]);
            v = f ? 0.0f : vn;
        }
        {
            const float vn = __fadd_rn(__fmul_rn(0.9f, v), c3);
            const bool f = (vn >= 1.0f);
            __builtin_nontemporal_store(vn, &voltage[i0 + 3*(size_t)LIF_D]);
            __builtin_nontemporal_store(f ? 1.0f : 0.0f, &spikes_out[i0 + 3*(size_t)LIF_D]);
            v = f ? 0.0f : vn;
        }
    }
}

extern "C" void kernel_launch(void* const* d_in, const int* in_sizes, int n_in,
                              void* d_out, int out_size, void* d_ws, size_t ws_size,
                              hipStream_t stream) {
    (void)in_sizes; (void)n_in; (void)out_size; (void)d_ws; (void)ws_size;

    // d_in[0] = prv_voltage (UNUSED by reference)
    const float* spikes = (const float*)d_in[1];   // (B,T,P) binary fp32
    const float* W      = (const float*)d_in[2];   // (P,D) fp32

    float* out        = (float*)d_out;
    float* voltage    = out;                       // N floats (stages currents)
    float* spikes_out = out + LIF_N;               // N floats

    lif_currents_kernel<<<LIF_B * LIF_T, 256, 0, stream>>>(spikes, W, voltage);
    lif_scan_kernel<<<(LIF_B * LIF_D) / 256, 256, 0, stream>>>(voltage, spikes_out);
}